// Round 2
// baseline (272.633 us; speedup 1.0000x reference)
//
#include <hip/hip_runtime.h>

// DerivativeNet direction='x' — one wave per (b,y) row, no LDS, no barriers.
// B=16, C=2, H=1024, W=1024 fp32. Each lane owns 4 chunks of 4 consecutive
// floats (chunk c, lane l -> w = c*256 + l*4 + j). All global accesses are
// float4 with lanes contiguous -> fully coalesced. Row cumsum = 4 chained
// 64-wide shfl scans; halos via shfl. Memory-bound: 320 MiB min traffic.

#define WDIM 1024

__global__ __launch_bounds__(256) void deriv_x_kernel(
    const float* __restrict__ u,
    const float* __restrict__ mask,
    float* __restrict__ out)
{
    const int wave = threadIdx.x >> 6;
    const int lane = threadIdx.x & 63;
    const int row  = blockIdx.x * 4 + wave;   // b*1024 + y
    const int b    = row >> 10;
    const int y    = row & 1023;

    const size_t mrow = (size_t)row * WDIM;                      // mask[b,0,y,:]
    const size_t u0r  = ((size_t)(b * 2) * WDIM + y) * WDIM;     // u[b,0,y,:]
    const size_t u1r  = u0r + (size_t)WDIM * WDIM;               // u[b,1,y,:]

    // ---- all loads issued up front: 12 independent dwordx4 in flight ----
    float4 mv[4], a[4], d[4];
    #pragma unroll
    for (int c = 0; c < 4; ++c) {
        const int off = c * 256 + lane * 4;
        mv[c] = *(const float4*)(mask + mrow + off);
        a[c]  = *(const float4*)(u + u0r + off);
        d[c]  = *(const float4*)(u + u1r + off);
    }

    // ---- pack mask to bits (values are exactly 0.0/1.0) ----
    int mb[4], cnt[4];
    #pragma unroll
    for (int c = 0; c < 4; ++c) {
        const int i0 = (int)mv[c].x, i1 = (int)mv[c].y;
        const int i2 = (int)mv[c].z, i3 = (int)mv[c].w;
        mb[c]  = i0 | (i1 << 1) | (i2 << 2) | (i3 << 3);
        cnt[c] = i0 + i1 + i2 + i3;
    }

    // ---- row cumsum: 4 chained 64-wide inclusive scans (integer, exact) ----
    int excl_c[4];
    int run = 0;
    #pragma unroll
    for (int c = 0; c < 4; ++c) {
        int v = cnt[c];
        #pragma unroll
        for (int o = 1; o < 64; o <<= 1) {
            const int n = __shfl_up(v, o, 64);
            if (lane >= o) v += n;
        }
        excl_c[c] = run + v - cnt[c];        // exclusive prefix at lane's chunk start
        run += __shfl(v, 63, 64);            // chunk total -> carry
    }
    const int total = run;

    const float inv2h = 50.0f;   // 1/(2h), h=0.01
    const float invh  = 100.0f;  // 1/h

    #pragma unroll
    for (int c = 0; c < 4; ++c) {
        const int bb = mb[c];
        const int i0 = bb & 1, i1 = (bb >> 1) & 1, i2 = (bb >> 2) & 1, i3 = (bb >> 3) & 1;

        // mask halo bits (zero-padded at row ends)
        const int upb = __shfl_up(bb, 1, 64);
        const int dnb = __shfl_down(bb, 1, 64);
        const int plb = (c > 0) ? (__shfl(mb[c - 1], 63, 64) >> 3) & 1 : 0;
        const int nfb = (c < 3) ? (__shfl(mb[c + 1], 0, 64)) & 1 : 0;
        const int ml  = (lane > 0)  ? (upb >> 3) & 1 : plb;
        const int mr  = (lane < 63) ? (dnb & 1)      : nfb;

        // eroded: 3-box == 3
        const float er0 = (ml + i0 + i1 == 3) ? 1.f : 0.f;
        const float er1 = (i0 + i1 + i2 == 3) ? 1.f : 0.f;
        const float er2 = (i1 + i2 + i3 == 3) ? 1.f : 0.f;
        const float er3 = (i2 + i3 + mr == 3) ? 1.f : 0.f;

        // cumsum per element; edge1: cs==1 (no mask AND, per reference);
        // edge2: mask && cs==rowtotal
        const int cs0 = excl_c[c] + i0;
        const int cs1 = cs0 + i1;
        const int cs2 = cs1 + i2;
        const int cs3 = cs2 + i3;
        const float e10 = (cs0 == 1) ? 1.f : 0.f;
        const float e11 = (cs1 == 1) ? 1.f : 0.f;
        const float e12 = (cs2 == 1) ? 1.f : 0.f;
        const float e13 = (cs3 == 1) ? 1.f : 0.f;
        const float e20 = (i0 && cs0 == total) ? 1.f : 0.f;
        const float e21 = (i1 && cs1 == total) ? 1.f : 0.f;
        const float e22 = (i2 && cs2 == total) ? 1.f : 0.f;
        const float e23 = (i3 && cs3 == total) ? 1.f : 0.f;

        const int off = c * 256 + lane * 4;

#define DO_CH(ARR, ROFF)                                                            \
        {                                                                           \
            const float4 V = ARR[c];                                                \
            const float upw = __shfl_up(ARR[c].w, 1, 64);                           \
            const float dnx = __shfl_down(ARR[c].x, 1, 64);                         \
            const float pl  = (c > 0) ? __shfl(ARR[c - 1].w, 63, 64) : 0.f;         \
            const float nf  = (c < 3) ? __shfl(ARR[c + 1].x, 0, 64) : 0.f;          \
            const float ul  = (lane > 0)  ? upw : pl;                               \
            const float ur  = (lane < 63) ? dnx : nf;                               \
            const float l0 = ul,  r0 = V.y;                                         \
            const float l1 = V.x, r1 = V.z;                                         \
            const float l2 = V.y, r2 = V.w;                                         \
            const float l3 = V.z, r3 = ur;                                          \
            float4 o;                                                               \
            o.x = er0*((r0-l0)*inv2h) + e10*((r0-V.x)*invh) + e20*((V.x-l0)*invh);  \
            o.y = er1*((r1-l1)*inv2h) + e11*((r1-V.y)*invh) + e21*((V.y-l1)*invh);  \
            o.z = er2*((r2-l2)*inv2h) + e12*((r2-V.z)*invh) + e22*((V.z-l2)*invh);  \
            o.w = er3*((r3-l3)*inv2h) + e13*((r3-V.w)*invh) + e23*((V.w-l3)*invh);  \
            *(float4*)(out + ROFF + off) = o;                                       \
        }

        DO_CH(a, u0r)
        DO_CH(d, u1r)
#undef DO_CH
    }
}

extern "C" void kernel_launch(void* const* d_in, const int* in_sizes, int n_in,
                              void* d_out, int out_size, void* d_ws, size_t ws_size,
                              hipStream_t stream) {
    const float* u    = (const float*)d_in[0];
    const float* mask = (const float*)d_in[1];
    float* out        = (float*)d_out;
    // 16384 rows, one wave per row, 4 waves (rows) per 256-thread block
    deriv_x_kernel<<<dim3(16 * 1024 / 4), dim3(256), 0, stream>>>(u, mask, out);
}